// Round 2
// baseline (19.827 us; speedup 1.0000x reference)
//
#include <hip/hip_runtime.h>
#include <math.h>

#define NFEAT 10
#define DTOT 160        // (2+8)*16
#define KDIM 32
#define EXB 64          // examples per block (4 waves x 16-row M-tile)
#define BLOCK 256
#define XPITCH 168      // padded bf16 row pitch (168*2B = 336B, breaks bank aliasing)

typedef __attribute__((ext_vector_type(8))) short bf16x8;
typedef __attribute__((ext_vector_type(4))) float f32x4;

__device__ inline unsigned short f2bf(float f) {
    unsigned u = __builtin_bit_cast(unsigned, f);
    u += 0x7FFFu + ((u >> 16) & 1u);          // round-to-nearest-even
    return (unsigned short)(u >> 16);
}
__device__ inline float bf2f(unsigned short h) {
    unsigned u = ((unsigned)h) << 16;
    return __builtin_bit_cast(float, u);
}

__global__ __launch_bounds__(BLOCK) void fm_kernel(
    const int* __restrict__ inputs,
    const float* __restrict__ user_table,
    const float* __restrict__ item_table,
    const float* __restrict__ feat_tables,
    const float* __restrict__ wvec,
    const float* __restrict__ bb,
    const float* __restrict__ k_mat,
    float* __restrict__ out)
{
    __shared__ unsigned short x_lds[EXB * XPITCH];  // 21 KB gathered x (bf16)
    __shared__ float kk2_lds[DTOT];                 // sum_k K[d][k]^2

    const int tid   = threadIdx.x;
    const int ebase = blockIdx.x * EXB;

    // ---- gather 64 examples x 160 floats, convert to bf16, stage in LDS ----
    for (int i = tid; i < EXB * 40; i += BLOCK) {
        int e  = i / 40;
        int r  = i - e * 40;          // float4 index within the 160-float row
        int f  = r >> 2;              // feature 0..9
        int j4 = r & 3;
        int idx = inputs[(ebase + e) * NFEAT + f];
        const float* src;
        if (f == 0)      src = user_table + (size_t)idx * 16;
        else if (f == 1) src = item_table + (size_t)idx * 16;
        else             src = feat_tables + ((size_t)(f - 2) * 10000 + (size_t)idx) * 16;
        float4 v = *(const float4*)(src + j4 * 4);
        ushort4 h;
        h.x = f2bf(v.x); h.y = f2bf(v.y); h.z = f2bf(v.z); h.w = f2bf(v.w);
        *(ushort4*)&x_lds[e * XPITCH + r * 4] = h;
    }

    // ---- kk2[d] = sum_k K[d][k]^2 ----
    if (tid < DTOT) {
        float acc = 0.f;
        #pragma unroll
        for (int kk = 0; kk < KDIM; ++kk) {
            float kv = k_mat[tid * KDIM + kk];
            acc = fmaf(kv, kv, acc);
        }
        kk2_lds[tid] = acc;
    }
    __syncthreads();

    const int lane = tid & 63;
    const int wid  = tid >> 6;        // wave id -> 16-example M-tile
    const int col  = lane & 15;       // N-col (k index within tile) / A-row
    const int kg   = lane >> 4;       // k-group 0..3 (8 contiguous K each)

    // ---- B fragments in registers, built once ----
    // layout: lane holds B[kg*8+j][col] for mfma_f32_16x16x32_bf16
    bf16x8 bk0[5], bk1[5], bw[5], bq[5];
    #pragma unroll
    for (int c = 0; c < 5; ++c) {
        int dbase = c * 32 + kg * 8;
        #pragma unroll
        for (int j = 0; j < 8; ++j) {
            int d = dbase + j;
            bk0[c][j] = (short)f2bf(k_mat[d * KDIM + col]);
            bk1[c][j] = (short)f2bf(k_mat[d * KDIM + 16 + col]);
            bw[c][j]  = (col == 0) ? (short)f2bf(wvec[d])     : (short)0;
            bq[c][j]  = (col == 0) ? (short)f2bf(kk2_lds[d])  : (short)0;
        }
    }

    // ---- MFMA main loop: 20 MFMAs per wave ----
    f32x4 acc0 = {0,0,0,0};   // s, k = 0..15
    f32x4 acc1 = {0,0,0,0};   // s, k = 16..31
    f32x4 accL = {0,0,0,0};   // linear = x . w        (col 0)
    f32x4 accT = {0,0,0,0};   // t      = x^2 . kk2    (col 0)

    const unsigned short* xrow = &x_lds[(wid * 16 + col) * XPITCH];
    #pragma unroll
    for (int c = 0; c < 5; ++c) {
        bf16x8 a = *(const bf16x8*)&xrow[c * 32 + kg * 8];
        bf16x8 a2;
        #pragma unroll
        for (int j = 0; j < 8; ++j) {
            float f = bf2f((unsigned short)a[j]);
            a2[j] = (short)f2bf(f * f);
        }
        acc0 = __builtin_amdgcn_mfma_f32_16x16x32_bf16(a,  bk0[c], acc0, 0, 0, 0);
        acc1 = __builtin_amdgcn_mfma_f32_16x16x32_bf16(a,  bk1[c], acc1, 0, 0, 0);
        accL = __builtin_amdgcn_mfma_f32_16x16x32_bf16(a,  bw[c],  accL, 0, 0, 0);
        accT = __builtin_amdgcn_mfma_f32_16x16x32_bf16(a2, bq[c],  accT, 0, 0, 0);
    }

    // ---- epilogue: per example r: sigmoid(lin + b + 0.5*(sum_k s^2 - t)) ----
    // C layout: col = lane&15 (k), row = kg*4 + reg (example within tile)
    float bval = bb[0];
    #pragma unroll
    for (int r = 0; r < 4; ++r) {
        float v = acc0[r] * acc0[r] + acc1[r] * acc1[r];   // s_k^2, this lane's k pair
        #pragma unroll
        for (int m = 1; m <= 8; m <<= 1)
            v += __shfl_xor(v, m, 64);                     // sum over 16 cols
        if (col == 0) {
            float z = accL[r] + bval + 0.5f * (v - accT[r]);
            out[ebase + wid * 16 + kg * 4 + r] = 1.0f / (1.0f + __expf(-z));
        }
    }
}

extern "C" void kernel_launch(void* const* d_in, const int* in_sizes, int n_in,
                              void* d_out, int out_size, void* d_ws, size_t ws_size,
                              hipStream_t stream) {
    const int*   inputs      = (const int*)  d_in[0];
    const float* user_table  = (const float*)d_in[1];
    const float* item_table  = (const float*)d_in[2];
    const float* feat_tables = (const float*)d_in[3];
    const float* w           = (const float*)d_in[4];
    const float* b           = (const float*)d_in[5];
    const float* k_mat       = (const float*)d_in[6];
    float* out = (float*)d_out;

    int nblocks = out_size / EXB;   // 16384 / 64 = 256
    fm_kernel<<<nblocks, BLOCK, 0, stream>>>(inputs, user_table, item_table,
                                             feat_tables, w, b, k_mat, out);
}

// Round 4
// 18.640 us; speedup vs baseline: 1.0637x; 1.0637x over previous
//
#include <hip/hip_runtime.h>
#include <math.h>

#define NFEAT 10
#define DTOT 160        // (2+8)*16
#define KDIM 32
#define DICT 10000

typedef __attribute__((ext_vector_type(8))) short bf16x8;
typedef __attribute__((ext_vector_type(4))) float f32x4;
typedef __attribute__((ext_vector_type(4))) unsigned u32x4;

__device__ inline unsigned short f2bf(float f) {
    unsigned u = __builtin_bit_cast(unsigned, f);
    u += 0x7FFFu + ((u >> 16) & 1u);          // round-to-nearest-even
    return (unsigned short)(u >> 16);
}

__device__ inline unsigned cvt2(float lo, float hi) {
    return (unsigned)f2bf(lo) | ((unsigned)f2bf(hi) << 16);   // packed 2x bf16
}

// ---- setup kernel: pack the 4 B-operand fragment sets (bf16) into ws ----
// ws16 layout: [(type*5 + c)*64 + lane]*8 + j ; type 0=K[:,0:16], 1=K[:,16:32],
// 2=w (col0 only), 3=kk2 (col0 only). d = c*32 + (lane>>4)*8 + j, col = lane&15.
__global__ __launch_bounds__(256) void fm_setup(
    const float* __restrict__ k_mat,
    const float* __restrict__ wvec,
    unsigned short* __restrict__ ws16)
{
    __shared__ float kk2[DTOT];
    const int tid = threadIdx.x;
    if (tid < DTOT) {
        const float4* row = (const float4*)(k_mat + tid * KDIM);
        float acc = 0.f;
        #pragma unroll
        for (int u = 0; u < 8; ++u) {
            float4 v = row[u];
            acc = fmaf(v.x, v.x, acc); acc = fmaf(v.y, v.y, acc);
            acc = fmaf(v.z, v.z, acc); acc = fmaf(v.w, v.w, acc);
        }
        kk2[tid] = acc;
    }
    __syncthreads();

    for (int i = tid; i < 4 * 5 * 64 * 8; i += 256) {
        int j    = i & 7;
        int lane = (i >> 3) & 63;
        int tc   = i >> 9;            // type*5 + c
        int c    = tc % 5;
        int type = tc / 5;
        int col  = lane & 15;
        int kg   = lane >> 4;
        int d    = c * 32 + kg * 8 + j;
        float val;
        if      (type == 0) val = k_mat[d * KDIM + col];
        else if (type == 1) val = k_mat[d * KDIM + 16 + col];
        else if (type == 2) val = (col == 0) ? wvec[d] : 0.f;
        else                val = (col == 0) ? kk2[d]  : 0.f;
        ws16[i] = f2bf(val);
    }
}

// ---- main kernel: no LDS, no syncthreads; wave = 16 examples ----
__global__ __launch_bounds__(256) void fm_main(
    const int* __restrict__ inputs,
    const float* __restrict__ user_table,
    const float* __restrict__ item_table,
    const float* __restrict__ feat_tables,
    const float* __restrict__ bb,
    const unsigned short* __restrict__ ws16,
    float* __restrict__ out)
{
    const int tid  = threadIdx.x;
    const int lane = tid & 63;
    const int gwid = blockIdx.x * 4 + (tid >> 6);   // global wave id, 0..1023
    const int col  = lane & 15;                     // example row within tile
    const int kg   = lane >> 4;                     // k-group 0..3
    const int e    = gwid * 16 + col;               // this lane's example
    const int fsel = kg >> 1;                       // 0: even features, 1: odd
    const int hoff = (kg & 1) * 8;                  // half of the 16-float embed

    // ---- index loads (5 features this lane touches) ----
    int idx[5];
    #pragma unroll
    for (int c = 0; c < 5; ++c)
        idx[c] = inputs[e * NFEAT + 2 * c + fsel];

    // ---- B fragments: 20 coalesced dwordx4, L1/L2-hit ----
    bf16x8 bk0[5], bk1[5], bw[5], bq[5];
    #pragma unroll
    for (int c = 0; c < 5; ++c) {
        bk0[c] = *(const bf16x8*)&ws16[((0 * 5 + c) * 64 + lane) * 8];
        bk1[c] = *(const bf16x8*)&ws16[((1 * 5 + c) * 64 + lane) * 8];
        bw[c]  = *(const bf16x8*)&ws16[((2 * 5 + c) * 64 + lane) * 8];
        bq[c]  = *(const bf16x8*)&ws16[((3 * 5 + c) * 64 + lane) * 8];
    }

    // ---- gather A fragments straight from the embedding tables ----
    bf16x8 a[5], a2[5];
    #pragma unroll
    for (int c = 0; c < 5; ++c) {
        const float* tbl = (c == 0)
            ? (fsel ? item_table : user_table)
            : (feat_tables + (size_t)(2 * c + fsel - 2) * (DICT * 16));
        const float* src = tbl + (size_t)idx[c] * 16 + hoff;
        float4 u0 = *(const float4*)src;
        float4 u1 = *(const float4*)(src + 4);
        u32x4 pa, pa2;
        pa[0]  = cvt2(u0.x, u0.y);           pa[1]  = cvt2(u0.z, u0.w);
        pa[2]  = cvt2(u1.x, u1.y);           pa[3]  = cvt2(u1.z, u1.w);
        pa2[0] = cvt2(u0.x*u0.x, u0.y*u0.y); pa2[1] = cvt2(u0.z*u0.z, u0.w*u0.w);
        pa2[2] = cvt2(u1.x*u1.x, u1.y*u1.y); pa2[3] = cvt2(u1.z*u1.z, u1.w*u1.w);
        a[c]  = __builtin_bit_cast(bf16x8, pa);
        a2[c] = __builtin_bit_cast(bf16x8, pa2);
    }

    // ---- 20 MFMAs ----
    f32x4 acc0 = {0,0,0,0};   // s, k = 0..15
    f32x4 acc1 = {0,0,0,0};   // s, k = 16..31
    f32x4 accL = {0,0,0,0};   // linear (col 0)
    f32x4 accT = {0,0,0,0};   // x^2 . kk2 (col 0)
    #pragma unroll
    for (int c = 0; c < 5; ++c) {
        acc0 = __builtin_amdgcn_mfma_f32_16x16x32_bf16(a[c],  bk0[c], acc0, 0, 0, 0);
        acc1 = __builtin_amdgcn_mfma_f32_16x16x32_bf16(a[c],  bk1[c], acc1, 0, 0, 0);
        accL = __builtin_amdgcn_mfma_f32_16x16x32_bf16(a[c],  bw[c],  accL, 0, 0, 0);
        accT = __builtin_amdgcn_mfma_f32_16x16x32_bf16(a2[c], bq[c],  accT, 0, 0, 0);
    }

    // ---- epilogue: C col = lane&15, row = kg*4 + r ----
    const float bval = bb[0];
    #pragma unroll
    for (int r = 0; r < 4; ++r) {
        float v = acc0[r] * acc0[r] + acc1[r] * acc1[r];
        #pragma unroll
        for (int m = 1; m <= 8; m <<= 1)
            v += __shfl_xor(v, m, 64);               // sum over the 16 cols
        if (col == 0) {
            float z = accL[r] + bval + 0.5f * (v - accT[r]);
            out[gwid * 16 + kg * 4 + r] = 1.0f / (1.0f + __expf(-z));
        }
    }
}

extern "C" void kernel_launch(void* const* d_in, const int* in_sizes, int n_in,
                              void* d_out, int out_size, void* d_ws, size_t ws_size,
                              hipStream_t stream) {
    const int*   inputs      = (const int*)  d_in[0];
    const float* user_table  = (const float*)d_in[1];
    const float* item_table  = (const float*)d_in[2];
    const float* feat_tables = (const float*)d_in[3];
    const float* w           = (const float*)d_in[4];
    const float* b           = (const float*)d_in[5];
    const float* k_mat       = (const float*)d_in[6];
    float* out = (float*)d_out;
    unsigned short* ws16 = (unsigned short*)d_ws;

    fm_setup<<<1, 256, 0, stream>>>(k_mat, w, ws16);

    int nblocks = out_size / 64;    // 16384 / (16 examples * 4 waves) = 256
    fm_main<<<nblocks, 256, 0, stream>>>(inputs, user_table, item_table,
                                         feat_tables, b, ws16, out);
}

// Round 5
// 12.044 us; speedup vs baseline: 1.6462x; 1.5477x over previous
//
#include <hip/hip_runtime.h>
#include <math.h>

#define NFEAT 10
#define DICT 10000

typedef __attribute__((ext_vector_type(8))) short bf16x8;
typedef __attribute__((ext_vector_type(4))) float f32x4;
typedef __attribute__((ext_vector_type(4))) unsigned u32x4;

__device__ inline unsigned short f2bf(float f) {
    unsigned u = __builtin_bit_cast(unsigned, f);
    u += 0x7FFFu + ((u >> 16) & 1u);          // round-to-nearest-even
    return (unsigned short)(u >> 16);
}
__device__ inline unsigned cvt2(float lo, float hi) {
    return (unsigned)f2bf(lo) | ((unsigned)f2bf(hi) << 16);   // packed 2x bf16
}

// Single fused kernel: no LDS, no __syncthreads, one launch.
// wave = 16 examples (M of one 16x16x32 MFMA tile); lane: col=lane&15 (example
// row for A / k-col for C), kg=lane>>4 (8-dim K-chunk group).
__global__ __launch_bounds__(256) void fm_fused(
    const int* __restrict__ inputs,
    const float* __restrict__ user_table,
    const float* __restrict__ item_table,
    const float* __restrict__ feat_tables,
    const float* __restrict__ wvec,
    const float* __restrict__ bb,
    const float* __restrict__ k_mat,
    float* __restrict__ out)
{
    const int tid  = threadIdx.x;
    const int lane = tid & 63;
    const int gwid = blockIdx.x * 4 + (tid >> 6);   // global wave id, 0..1023
    const int col  = lane & 15;
    const int kg   = lane >> 4;
    const int e    = gwid * 16 + col;               // this lane's example
    const int fsel = kg >> 1;                       // even/odd feature
    const int hoff = (kg & 1) * 8;                  // which half of the embed

    // ---- index loads (5 per lane) ----
    int idx[5];
    #pragma unroll
    for (int c = 0; c < 5; ++c)
        idx[c] = inputs[e * NFEAT + 2 * c + fsel];

    // ---- gather x slices in f32 (issued early, independent) ----
    float4 u0[5], u1[5];
    #pragma unroll
    for (int c = 0; c < 5; ++c) {
        const float* tbl = (c == 0)
            ? (fsel ? item_table : user_table)
            : (feat_tables + (size_t)(2 * c + fsel - 2) * (DICT * 16));
        const float* src = tbl + (size_t)idx[c] * 16 + hoff;
        u0[c] = *(const float4*)src;
        u1[c] = *(const float4*)(src + 4);
    }

    // ---- B fragments from k_mat (20 KB, L1-resident) + squared variants ----
    // lane holds K[d][col] / K[d][col+16], d = c*32 + kg*8 + j
    bf16x8 bk0[5], bk1[5], bq0[5], bq1[5];
    #pragma unroll
    for (int c = 0; c < 5; ++c) {
        const int dbase = c * 32 + kg * 8;
        float f0[8], f1[8];
        #pragma unroll
        for (int j = 0; j < 8; ++j) {
            f0[j] = k_mat[(dbase + j) * 32 + col];
            f1[j] = k_mat[(dbase + j) * 32 + 16 + col];
        }
        u32x4 p0, p1, q0, q1;
        #pragma unroll
        for (int j = 0; j < 4; ++j) {
            p0[j] = cvt2(f0[2*j],          f0[2*j+1]);
            p1[j] = cvt2(f1[2*j],          f1[2*j+1]);
            q0[j] = cvt2(f0[2*j]*f0[2*j],  f0[2*j+1]*f0[2*j+1]);
            q1[j] = cvt2(f1[2*j]*f1[2*j],  f1[2*j+1]*f1[2*j+1]);
        }
        bk0[c] = __builtin_bit_cast(bf16x8, p0);
        bk1[c] = __builtin_bit_cast(bf16x8, p1);
        bq0[c] = __builtin_bit_cast(bf16x8, q0);
        bq1[c] = __builtin_bit_cast(bf16x8, q1);
    }

    // ---- linear term in exact f32 (per-lane slice of x . w) ----
    float lin = 0.f;
    #pragma unroll
    for (int c = 0; c < 5; ++c) {
        const int dbase = c * 32 + kg * 8;
        float4 w0 = *(const float4*)&wvec[dbase];
        float4 w1 = *(const float4*)&wvec[dbase + 4];
        lin = fmaf(u0[c].x, w0.x, lin); lin = fmaf(u0[c].y, w0.y, lin);
        lin = fmaf(u0[c].z, w0.z, lin); lin = fmaf(u0[c].w, w0.w, lin);
        lin = fmaf(u1[c].x, w1.x, lin); lin = fmaf(u1[c].y, w1.y, lin);
        lin = fmaf(u1[c].z, w1.z, lin); lin = fmaf(u1[c].w, w1.w, lin);
    }
    lin += __shfl_xor(lin, 16, 64);
    lin += __shfl_xor(lin, 32, 64);        // lane now holds full lin[e=col]

    // ---- A fragments + 20 MFMAs ----
    f32x4 acc0  = {0,0,0,0};   // s,  k = col
    f32x4 acc1  = {0,0,0,0};   // s,  k = col+16
    f32x4 accT0 = {0,0,0,0};   // x^2 . K^2, k = col
    f32x4 accT1 = {0,0,0,0};   // x^2 . K^2, k = col+16
    #pragma unroll
    for (int c = 0; c < 5; ++c) {
        u32x4 pa, pa2;
        pa[0]  = cvt2(u0[c].x, u0[c].y);  pa[1]  = cvt2(u0[c].z, u0[c].w);
        pa[2]  = cvt2(u1[c].x, u1[c].y);  pa[3]  = cvt2(u1[c].z, u1[c].w);
        pa2[0] = cvt2(u0[c].x*u0[c].x, u0[c].y*u0[c].y);
        pa2[1] = cvt2(u0[c].z*u0[c].z, u0[c].w*u0[c].w);
        pa2[2] = cvt2(u1[c].x*u1[c].x, u1[c].y*u1[c].y);
        pa2[3] = cvt2(u1[c].z*u1[c].z, u1[c].w*u1[c].w);
        bf16x8 a  = __builtin_bit_cast(bf16x8, pa);
        bf16x8 a2 = __builtin_bit_cast(bf16x8, pa2);
        acc0  = __builtin_amdgcn_mfma_f32_16x16x32_bf16(a,  bk0[c], acc0,  0, 0, 0);
        acc1  = __builtin_amdgcn_mfma_f32_16x16x32_bf16(a,  bk1[c], acc1,  0, 0, 0);
        accT0 = __builtin_amdgcn_mfma_f32_16x16x32_bf16(a2, bq0[c], accT0, 0, 0, 0);
        accT1 = __builtin_amdgcn_mfma_f32_16x16x32_bf16(a2, bq1[c], accT1, 0, 0, 0);
    }

    // ---- epilogue: C row = kg*4+r (example), col = k ----
    const float bval = bb[0];
    #pragma unroll
    for (int r = 0; r < 4; ++r) {
        float v = acc0[r]*acc0[r] + acc1[r]*acc1[r] - accT0[r] - accT1[r];
        #pragma unroll
        for (int m = 1; m <= 8; m <<= 1)
            v += __shfl_xor(v, m, 64);             // sum over 16 k-cols
        float lm = __shfl(lin, kg * 4 + r, 64);    // lin for example kg*4+r
        if (col == 0) {
            float z = lm + bval + 0.5f * v;
            out[gwid * 16 + kg * 4 + r] = 1.0f / (1.0f + __expf(-z));
        }
    }
}

extern "C" void kernel_launch(void* const* d_in, const int* in_sizes, int n_in,
                              void* d_out, int out_size, void* d_ws, size_t ws_size,
                              hipStream_t stream) {
    const int*   inputs      = (const int*)  d_in[0];
    const float* user_table  = (const float*)d_in[1];
    const float* item_table  = (const float*)d_in[2];
    const float* feat_tables = (const float*)d_in[3];
    const float* w           = (const float*)d_in[4];
    const float* b           = (const float*)d_in[5];
    const float* k_mat       = (const float*)d_in[6];
    float* out = (float*)d_out;

    int nblocks = out_size / 64;    // 16384 / (16 examples * 4 waves) = 256
    fm_fused<<<nblocks, 256, 0, stream>>>(inputs, user_table, item_table,
                                          feat_tables, w, b, k_mat, out);
}